// Round 5
// baseline (148.265 us; speedup 1.0000x reference)
//
#include <hip/hip_runtime.h>

// LGA2 fused: out = LGA(LGA(x,f),f), radius=2 (25 taps), fp32.
// x: [N=2, C=64, H=256, W=512], f: [N, 25, H, W], out like x.
//
// R4 vs R3:
//  - mapping r=tid>>4, s=tid&15: wave = 4 full rows x 16 quad-strips; LDS row
//    stride 68 dwords (17 quads, odd) -> b128 reads hit all 8 bank-quads
//    exactly 8 lanes each (zero extra conflict). Staging is LINEAR (quad l ->
//    dword 4l): contiguous ds_write_b128, conflict-free.
//  - launch_bounds(256,2): VGPR cap 256 so fr[25][4] (100 regs) stays
//    resident (R3 spilled at cap 170: VGPR_Count=84).
//  - raw lgkm-only barrier between p1 and p2 keeps the global prefetch loads
//    in flight across it (overlap = p1+p2 instead of p1).
// Tile: temp 16x64 (global cols ow0-2..ow0+61), out 12x60. x region 20x68.

#define OH 12
#define OW 60
#define STS 68          // row stride in dwords for BOTH sx and st
#define SXN (20 * STS)  // 1360 dwords per x buffer

__global__ __launch_bounds__(256, 2)
void lga2_fused(const float* __restrict__ x, const float* __restrict__ f,
                float* __restrict__ out,
                int N, int C, int H, int W, int CPB) {
    const int tid = threadIdx.x;
    const int r = tid >> 4;            // temp-region row 0..15
    const int s = tid & 15;            // quad-strip 0..15 (temp cols 4s..4s+3)
    const int oh0 = blockIdx.y * OH;
    const int ow0 = blockIdx.x * OW;
    const int CG = C / CPB;
    const int n  = blockIdx.z / CG;
    const int c0 = (blockIdx.z % CG) * CPB;
    const int HW = H * W;

    __shared__ float sx[2][SXN];
    __shared__ float st[16 * STS];     // [2 guard][64 temp][2 guard] per row

    // zero temp guard columns (dwords 0,1,66,67 of each row) once
    if (tid < 64) {
        int zr = tid >> 2, q = tid & 3;
        st[zr * STS + (q < 2 ? q : q + 64)] = 0.0f;
    }

    // ---- filter registers fr[tap][k] at (gh_f, gwb+k); edge -> 0 (zero-pad) ----
    const int gh_f = oh0 - 2 + r;          // this thread's temp/out row (global)
    const int gwb  = ow0 - 2 + 4 * s;      // quad's first global col (== 2 mod 4)
    const bool rowok = (gh_f >= 0) && (gh_f < H);
    const bool fp0ok = rowok && (gwb >= 0) && (gwb + 1 < W);   // pair never splits
    const bool fp1ok = rowok && (gwb + 3 < W);
    float fr[25][4];
    {
        const float* fbase = f + (size_t)(n * 25) * HW + (size_t)(rowok ? gh_f : 0) * W;
        #pragma unroll
        for (int t = 0; t < 25; ++t) {
            const float* fp = fbase + (size_t)t * HW;
            float2 v01 = fp0ok ? *(const float2*)(fp + gwb)     : make_float2(0.f, 0.f);
            float2 v23 = fp1ok ? *(const float2*)(fp + gwb + 2) : make_float2(0.f, 0.f);
            fr[t][0] = v01.x; fr[t][1] = v01.y; fr[t][2] = v23.x; fr[t][3] = v23.y;
            asm volatile("" : "+v"(fr[t][0]), "+v"(fr[t][1]), "+v"(fr[t][2]), "+v"(fr[t][3]));
        }
    }

    // ---- staging geometry: 340 quads, LINEAR lds (quad l -> dword 4l) ----
    const int q1i = tid + 256;
    const bool has1 = (tid < 340 - 256);
    const int row0 = tid / 17, v0 = tid - row0 * 17;
    const int row1 = q1i / 17, v1 = q1i - row1 * 17;
    const int g0h = oh0 - 4 + row0, g0c = ow0 - 4 + 4 * v0;
    const int g1h = oh0 - 4 + row1, g1c = ow0 - 4 + 4 * v1;
    const bool ok0 = (g0h >= 0) && (g0h < H) && (g0c >= 0) && (g0c + 3 < W);
    const bool ok1 = has1 && (g1h >= 0) && (g1h < H) && (g1c >= 0) && (g1c + 3 < W);
    const int off0 = ok0 ? (g0h * W + g0c) : 0;
    const int off1 = ok1 ? (g1h * W + g1c) : 0;
    const int l0 = 4 * tid;
    const int l1 = 4 * q1i;

    const float4 zero4 = make_float4(0.f, 0.f, 0.f, 0.f);
    const float* xc = x + (size_t)(n * C + c0) * HW;

    // prologue: stage channel c0 into buffer 0
    {
        float4 p0 = ok0 ? *(const float4*)(xc + off0) : zero4;
        *(float4*)&sx[0][l0] = p0;
        if (has1) {
            float4 p1v = ok1 ? *(const float4*)(xc + off1) : zero4;
            *(float4*)&sx[0][l1] = p1v;
        }
    }
    __syncthreads();

    int cur = 0;
    for (int cc = 0; cc < CPB; ++cc) {
        // ---- issue prefetch for channel cc+1 (lands after p2) ----
        float4 n0 = zero4, n1 = zero4;
        const bool pf = (cc + 1 < CPB);
        if (pf) {
            const float* xn = xc + (size_t)(cc + 1) * HW;
            if (ok0) n0 = *(const float4*)(xn + off0);
            if (ok1) n1 = *(const float4*)(xn + off1);
        }

        // ---- pass 1: temp at region (r, 4s..4s+3) ----
        {
            const float* base = sx[cur];
            float a0 = 0.f, a1 = 0.f, a2 = 0.f, a3 = 0.f;
            #pragma unroll
            for (int i = 0; i < 5; ++i) {
                const float* xr = base + (r + i) * STS + 4 * s;   // 16B aligned
                const float4 xa = *(const float4*)xr;
                const float4 xb = *(const float4*)(xr + 4);
                const float xv[8] = {xa.x, xa.y, xa.z, xa.w, xb.x, xb.y, xb.z, xb.w};
                #pragma unroll
                for (int j = 0; j < 5; ++j) {
                    a0 = fmaf(fr[i * 5 + j][0], xv[j + 0], a0);
                    a1 = fmaf(fr[i * 5 + j][1], xv[j + 1], a1);
                    a2 = fmaf(fr[i * 5 + j][2], xv[j + 2], a2);
                    a3 = fmaf(fr[i * 5 + j][3], xv[j + 3], a3);
                }
            }
            *(float2*)&st[r * STS + 2 + 4 * s] = make_float2(a0, a1);
            *(float2*)&st[r * STS + 4 + 4 * s] = make_float2(a2, a3);
        }

        // raw barrier: LDS-only drain; global prefetch stays in flight
        asm volatile("s_waitcnt lgkmcnt(0)" ::: "memory");
        __builtin_amdgcn_s_barrier();
        asm volatile("" ::: "memory");

        // ---- pass 2: out rows oh0..oh0+11, cols from temp interior ----
        if (r >= 2 && r <= 13 && gh_f < H) {
            float o0 = 0.f, o1 = 0.f, o2 = 0.f, o3 = 0.f;
            #pragma unroll
            for (int i = 0; i < 5; ++i) {
                const float* tr_ = st + (r - 2 + i) * STS + 4 * s;  // 16B aligned
                const float4 ta = *(const float4*)tr_;
                const float4 tb = *(const float4*)(tr_ + 4);
                const float tv[8] = {ta.x, ta.y, ta.z, ta.w, tb.x, tb.y, tb.z, tb.w};
                #pragma unroll
                for (int j = 0; j < 5; ++j) {
                    o0 = fmaf(fr[i * 5 + j][0], tv[j + 0], o0);
                    o1 = fmaf(fr[i * 5 + j][1], tv[j + 1], o1);
                    o2 = fmaf(fr[i * 5 + j][2], tv[j + 2], o2);
                    o3 = fmaf(fr[i * 5 + j][3], tv[j + 3], o3);
                }
            }
            float* op = out + ((size_t)(n * C + c0 + cc) * H + gh_f) * W + gwb;
            if (s >= 1 && gwb + 1 < W)  *(float2*)op       = make_float2(o0, o1);
            if (s <= 14 && gwb + 3 < W) *(float2*)(op + 2) = make_float2(o2, o3);
        }

        // ---- land prefetch into the other buffer ----
        if (pf) {
            float* d = sx[cur ^ 1];
            *(float4*)&d[l0] = n0;
            if (has1) *(float4*)&d[l1] = n1;
        }
        __syncthreads();   // full drain: st reads done, next sx ready
        cur ^= 1;
    }
}

extern "C" void kernel_launch(void* const* d_in, const int* in_sizes, int n_in,
                              void* d_out, int out_size, void* d_ws, size_t ws_size,
                              hipStream_t stream) {
    const float* x = (const float*)d_in[0];
    const float* f = (const float*)d_in[1];
    float* out = (float*)d_out;

    const int N = 2, C = 64, H = 256, W = 512;
    const int CPB = 32;
    const int CG = C / CPB;                    // 2

    dim3 grid((W + OW - 1) / OW,               // 9
              (H + OH - 1) / OH,               // 22
              N * CG);                         // 4  -> 792 blocks
    lga2_fused<<<grid, 256, 0, stream>>>(x, f, out, N, C, H, W, CPB);
}

// Round 6
// 140.424 us; speedup vs baseline: 1.0558x; 1.0558x over previous
//
#include <hip/hip_runtime.h>

// LGA2 fused: out = LGA(LGA(x,f),f), radius=2 (25 taps), fp32.
// x: [N=2, C=64, H=256, W=512], f: [N, 25, H, W], out like x.
//
// R6 vs R5:
//  - amdgpu_waves_per_eu(2,2): min=max=2 removes the RA's occupancy-driven
//    spill heuristic (R5: VGPR_Count=92 < the 100 fr values => scratch
//    spill; launch_bounds(256,2) only sets the MIN, allocator still aimed
//    at 5 waves/EU). Budget is now 256 VGPRs; fr[25][4]+working ~150 fits.
//  - CPB=64: filters loaded once per tile (was twice); grid 9*22*2=396.
// Tile: temp 16x64 (global cols ow0-2..ow0+61), out 12x60. x region 20x68.
// LDS: stride 68 dwords everywhere; 16x16 thread map (wave = 4 rows x 16
// quad-strips) -> even bank spread on b128 reads; staging linear.

#define OH 12
#define OW 60
#define STS 68          // row stride in dwords for BOTH sx and st
#define SXN (20 * STS)  // 1360 dwords per x buffer

__global__ __launch_bounds__(256)
__attribute__((amdgpu_waves_per_eu(2, 2)))
void lga2_fused(const float* __restrict__ x, const float* __restrict__ f,
                float* __restrict__ out,
                int N, int C, int H, int W, int CPB) {
    const int tid = threadIdx.x;
    const int r = tid >> 4;            // temp-region row 0..15
    const int s = tid & 15;            // quad-strip 0..15 (temp cols 4s..4s+3)
    const int oh0 = blockIdx.y * OH;
    const int ow0 = blockIdx.x * OW;
    const int n  = blockIdx.z;         // CPB == C: one block covers all channels
    const int HW = H * W;

    __shared__ float sx[2][SXN];
    __shared__ float st[16 * STS];     // [2 guard][64 temp][2 guard] per row

    // zero temp guard columns (dwords 0,1,66,67 of each row) once
    if (tid < 64) {
        int zr = tid >> 2, q = tid & 3;
        st[zr * STS + (q < 2 ? q : q + 64)] = 0.0f;
    }

    // ---- filter registers fr[tap][k] at (gh_f, gwb+k); edge -> 0 (zero-pad) ----
    const int gh_f = oh0 - 2 + r;          // this thread's temp/out row (global)
    const int gwb  = ow0 - 2 + 4 * s;      // quad's first global col (== 2 mod 4)
    const bool rowok = (gh_f >= 0) && (gh_f < H);
    const bool fp0ok = rowok && (gwb >= 0) && (gwb + 1 < W);   // pair never splits
    const bool fp1ok = rowok && (gwb + 3 < W);
    float fr[25][4];
    {
        const float* fbase = f + (size_t)(n * 25) * HW + (size_t)(rowok ? gh_f : 0) * W;
        #pragma unroll
        for (int t = 0; t < 25; ++t) {
            const float* fp = fbase + (size_t)t * HW;
            float2 v01 = fp0ok ? *(const float2*)(fp + gwb)     : make_float2(0.f, 0.f);
            float2 v23 = fp1ok ? *(const float2*)(fp + gwb + 2) : make_float2(0.f, 0.f);
            fr[t][0] = v01.x; fr[t][1] = v01.y; fr[t][2] = v23.x; fr[t][3] = v23.y;
            asm volatile("" : "+v"(fr[t][0]), "+v"(fr[t][1]), "+v"(fr[t][2]), "+v"(fr[t][3]));
        }
    }

    // ---- staging geometry: 340 quads, LINEAR lds (quad l -> dword 4l) ----
    const int q1i = tid + 256;
    const bool has1 = (tid < 340 - 256);
    const int row0 = tid / 17, v0 = tid - row0 * 17;
    const int row1 = q1i / 17, v1 = q1i - row1 * 17;
    const int g0h = oh0 - 4 + row0, g0c = ow0 - 4 + 4 * v0;
    const int g1h = oh0 - 4 + row1, g1c = ow0 - 4 + 4 * v1;
    const bool ok0 = (g0h >= 0) && (g0h < H) && (g0c >= 0) && (g0c + 3 < W);
    const bool ok1 = has1 && (g1h >= 0) && (g1h < H) && (g1c >= 0) && (g1c + 3 < W);
    const int off0 = ok0 ? (g0h * W + g0c) : 0;
    const int off1 = ok1 ? (g1h * W + g1c) : 0;
    const int l0 = 4 * tid;
    const int l1 = 4 * q1i;

    const float4 zero4 = make_float4(0.f, 0.f, 0.f, 0.f);
    const float* xc = x + (size_t)(n * C) * HW;

    // prologue: stage channel 0 into buffer 0
    {
        float4 p0 = ok0 ? *(const float4*)(xc + off0) : zero4;
        *(float4*)&sx[0][l0] = p0;
        if (has1) {
            float4 p1v = ok1 ? *(const float4*)(xc + off1) : zero4;
            *(float4*)&sx[0][l1] = p1v;
        }
    }
    __syncthreads();

    int cur = 0;
    for (int cc = 0; cc < CPB; ++cc) {
        // ---- issue prefetch for channel cc+1 (lands after p2) ----
        float4 n0 = zero4, n1 = zero4;
        const bool pf = (cc + 1 < CPB);
        if (pf) {
            const float* xn = xc + (size_t)(cc + 1) * HW;
            if (ok0) n0 = *(const float4*)(xn + off0);
            if (ok1) n1 = *(const float4*)(xn + off1);
        }

        // ---- pass 1: temp at region (r, 4s..4s+3) ----
        {
            const float* base = sx[cur];
            float a0 = 0.f, a1 = 0.f, a2 = 0.f, a3 = 0.f;
            #pragma unroll
            for (int i = 0; i < 5; ++i) {
                const float* xr = base + (r + i) * STS + 4 * s;   // 16B aligned
                const float4 xa = *(const float4*)xr;
                const float4 xb = *(const float4*)(xr + 4);
                const float xv[8] = {xa.x, xa.y, xa.z, xa.w, xb.x, xb.y, xb.z, xb.w};
                #pragma unroll
                for (int j = 0; j < 5; ++j) {
                    a0 = fmaf(fr[i * 5 + j][0], xv[j + 0], a0);
                    a1 = fmaf(fr[i * 5 + j][1], xv[j + 1], a1);
                    a2 = fmaf(fr[i * 5 + j][2], xv[j + 2], a2);
                    a3 = fmaf(fr[i * 5 + j][3], xv[j + 3], a3);
                }
            }
            *(float2*)&st[r * STS + 2 + 4 * s] = make_float2(a0, a1);
            *(float2*)&st[r * STS + 4 + 4 * s] = make_float2(a2, a3);
        }

        // raw barrier: LDS-only drain; global prefetch stays in flight
        asm volatile("s_waitcnt lgkmcnt(0)" ::: "memory");
        __builtin_amdgcn_s_barrier();
        asm volatile("" ::: "memory");

        // ---- pass 2: out rows oh0..oh0+11, cols from temp interior ----
        if (r >= 2 && r <= 13 && gh_f < H) {
            float o0 = 0.f, o1 = 0.f, o2 = 0.f, o3 = 0.f;
            #pragma unroll
            for (int i = 0; i < 5; ++i) {
                const float* tr_ = st + (r - 2 + i) * STS + 4 * s;  // 16B aligned
                const float4 ta = *(const float4*)tr_;
                const float4 tb = *(const float4*)(tr_ + 4);
                const float tv[8] = {ta.x, ta.y, ta.z, ta.w, tb.x, tb.y, tb.z, tb.w};
                #pragma unroll
                for (int j = 0; j < 5; ++j) {
                    o0 = fmaf(fr[i * 5 + j][0], tv[j + 0], o0);
                    o1 = fmaf(fr[i * 5 + j][1], tv[j + 1], o1);
                    o2 = fmaf(fr[i * 5 + j][2], tv[j + 2], o2);
                    o3 = fmaf(fr[i * 5 + j][3], tv[j + 3], o3);
                }
            }
            float* op = out + ((size_t)(n * C + cc) * H + gh_f) * W + gwb;
            if (s >= 1 && gwb + 1 < W)  *(float2*)op       = make_float2(o0, o1);
            if (s <= 14 && gwb + 3 < W) *(float2*)(op + 2) = make_float2(o2, o3);
        }

        // ---- land prefetch into the other buffer ----
        if (pf) {
            float* d = sx[cur ^ 1];
            *(float4*)&d[l0] = n0;
            if (has1) *(float4*)&d[l1] = n1;
        }
        __syncthreads();   // full drain: st reads done, next sx ready
        cur ^= 1;
    }
}

extern "C" void kernel_launch(void* const* d_in, const int* in_sizes, int n_in,
                              void* d_out, int out_size, void* d_ws, size_t ws_size,
                              hipStream_t stream) {
    const float* x = (const float*)d_in[0];
    const float* f = (const float*)d_in[1];
    float* out = (float*)d_out;

    const int N = 2, C = 64, H = 256, W = 512;
    const int CPB = 64;                        // all channels in one block

    dim3 grid((W + OW - 1) / OW,               // 9
              (H + OH - 1) / OH,               // 22
              N);                              // 2  -> 396 blocks
    lga2_fused<<<grid, 256, 0, stream>>>(x, f, out, N, C, H, W, CPB);
}

// Round 7
// 93.983 us; speedup vs baseline: 1.5776x; 1.4941x over previous
//
#include <hip/hip_runtime.h>

// LGA2 fused: out = LGA(LGA(x,f),f), radius=2 (25 taps), fp32.
// x: [N=2, C=64, H=256, W=512], f: [N, 25, H, W], out like x.
//
// R7: tap-row split producer/partial structure to kill the filter-cache
// spill (R2-R6: VGPR_Count 84-92 < 100 fr values => scratch reloads).
//  - 512 threads: set A (tid<256) = filter rows 0-2 (15 taps, F0..F14),
//    set B = filter rows 3-4 (10 taps, reusing names F0..F9 => shared regs).
//    Max live filter regs 60 + ~35 working: fits ANY occupancy target.
//  - Filters in NAMED f4 SSA vars (no array => nothing for the RA to
//    keep in scratch).
//  - Per pass: A writes partial to sp, B adds its partial and finalizes.
//    4 lgkm-only barriers per channel; global prefetch stays in flight.
// Tile: temp 16x64, out 12x60, x region 20x68, stride 68 dwords.

typedef float f4 __attribute__((ext_vector_type(4)));
typedef float f2 __attribute__((ext_vector_type(2)));

#define OH 12
#define OW 60
#define STS 68
#define SXN (20 * STS)   // 1360 dwords per x buffer

#define TAPF(F,u0,u1,u2,u3) { a0=fmaf(F.x,u0,a0); a1=fmaf(F.y,u1,a1); \
                              a2=fmaf(F.z,u2,a2); a3=fmaf(F.w,u3,a3); }
#define ROW5(Fa,Fb,Fc,Fd,Fe,P) { const f4 xa=*(const f4*)(P); const f4 xb=*(const f4*)((P)+4); \
  TAPF(Fa,xa.x,xa.y,xa.z,xa.w) TAPF(Fb,xa.y,xa.z,xa.w,xb.x) TAPF(Fc,xa.z,xa.w,xb.x,xb.y) \
  TAPF(Fd,xa.w,xb.x,xb.y,xb.z) TAPF(Fe,xb.x,xb.y,xb.z,xb.w) }

// lgkm-only barrier: LDS ordered, global prefetch loads stay in flight
#define LBAR() { asm volatile("s_waitcnt lgkmcnt(0)" ::: "memory"); \
                 __builtin_amdgcn_s_barrier(); asm volatile("" ::: "memory"); }

__global__ __launch_bounds__(512)
void lga2_fused(const float* __restrict__ x, const float* __restrict__ f,
                float* __restrict__ out, int N, int C, int H, int W, int CPB) {
    const int tid = threadIdx.x;
    const bool isA = (tid < 256);
    const int t = tid & 255;
    const int r = t >> 4;              // temp-region row 0..15
    const int s = t & 15;              // quad-strip 0..15
    const int oh0 = blockIdx.y * OH;
    const int ow0 = blockIdx.x * OW;
    const int CG = C / CPB;
    const int n  = blockIdx.z / CG;
    const int c0 = (blockIdx.z % CG) * CPB;
    const int HW = H * W;

    __shared__ float sx[2][SXN];
    __shared__ float st[16 * STS];   // [2 guard][64 temp][2 guard] per row
    __shared__ float sp[16 * STS];   // partial-sum exchange (quads at 4s)

    if (tid < 64) {                  // zero temp guard cols once
        int zr = tid >> 2, q = tid & 3;
        st[zr * STS + (q < 2 ? q : q + 64)] = 0.0f;
    }

    // ---- filter registers (named SSA f4 vars) ----
    const int gh_f = oh0 - 2 + r;
    const int gwb  = ow0 - 2 + 4 * s;
    const bool rowok = (gh_f >= 0) && (gh_f < H);
    const bool p0ok = rowok && (gwb >= 0) && (gwb + 1 < W);
    const bool p1ok = rowok && (gwb + 3 < W);
    const float* fb = f + (size_t)(n * 25) * HW + (size_t)(rowok ? gh_f : 0) * W;

#define LDF(T) ({ f2 u_ = p0ok ? *(const f2*)(fb + (size_t)(T) * HW + gwb)     : f2{0.f, 0.f}; \
                  f2 v_ = p1ok ? *(const f2*)(fb + (size_t)(T) * HW + gwb + 2) : f2{0.f, 0.f}; \
                  f4{u_.x, u_.y, v_.x, v_.y}; })
#define PIN(F) asm volatile("" : "+v"(F));

    f4 F0,F1,F2,F3,F4,F5,F6,F7,F8,F9,F10,F11,F12,F13,F14;
    F10 = F11 = F12 = F13 = F14 = f4{0.f,0.f,0.f,0.f};
    if (isA) {
        F0=LDF(0); F1=LDF(1); F2=LDF(2); F3=LDF(3); F4=LDF(4);
        F5=LDF(5); F6=LDF(6); F7=LDF(7); F8=LDF(8); F9=LDF(9);
        F10=LDF(10); F11=LDF(11); F12=LDF(12); F13=LDF(13); F14=LDF(14);
        PIN(F10) PIN(F11) PIN(F12) PIN(F13) PIN(F14)
    } else {
        F0=LDF(15); F1=LDF(16); F2=LDF(17); F3=LDF(18); F4=LDF(19);
        F5=LDF(20); F6=LDF(21); F7=LDF(22); F8=LDF(23); F9=LDF(24);
    }
    PIN(F0) PIN(F1) PIN(F2) PIN(F3) PIN(F4)
    PIN(F5) PIN(F6) PIN(F7) PIN(F8) PIN(F9)

    // ---- staging geometry: 340 quads, one per thread (tid<340), linear ----
    const bool stg = (tid < 340);
    const int row0 = tid / 17, v0 = tid - row0 * 17;
    const int g0h = oh0 - 4 + row0, g0c = ow0 - 4 + 4 * v0;
    const bool ok0 = stg && (g0h >= 0) && (g0h < H) && (g0c >= 0) && (g0c + 3 < W);
    const int off0 = ok0 ? (g0h * W + g0c) : 0;
    const int l0 = 4 * tid;
    const f4 z4 = f4{0.f, 0.f, 0.f, 0.f};
    const float* xc = x + (size_t)(n * C + c0) * HW;

    if (stg) {                         // prologue: stage channel 0
        f4 p = ok0 ? *(const f4*)(xc + off0) : z4;
        *(f4*)&sx[0][l0] = p;
    }
    __syncthreads();

    int cur = 0;
    for (int cc = 0; cc < CPB; ++cc) {
        // issue prefetch for channel cc+1 (value used only at iter end)
        f4 nx = z4;
        const bool pf = (cc + 1 < CPB);
        if (pf && ok0) nx = *(const f4*)(xc + (size_t)(cc + 1) * HW + off0);

        // ---- pass 1 partials ----
        float a0 = 0.f, a1 = 0.f, a2 = 0.f, a3 = 0.f;
        {
            const float* sxp = sx[cur];
            if (isA) {
                const float* P0 = sxp + r * STS + 4 * s;
                ROW5(F0,F1,F2,F3,F4,   P0)
                ROW5(F5,F6,F7,F8,F9,   P0 + STS)
                ROW5(F10,F11,F12,F13,F14, P0 + 2 * STS)
                *(f4*)&sp[r * STS + 4 * s] = f4{a0, a1, a2, a3};
            } else {
                const float* P3 = sxp + (r + 3) * STS + 4 * s;
                ROW5(F0,F1,F2,F3,F4,   P3)
                ROW5(F5,F6,F7,F8,F9,   P3 + STS)
            }
        }
        LBAR();   // b1: sp (pass-1 A-partials) visible

        if (!isA) {                    // combine -> temp
            f4 pa = *(const f4*)&sp[r * STS + 4 * s];
            *(f2*)&st[r * STS + 2 + 4 * s] = f2{pa.x + a0, pa.y + a1};
            *(f2*)&st[r * STS + 4 + 4 * s] = f2{pa.z + a2, pa.w + a3};
        }
        LBAR();   // b2: st (temp) visible

        // ---- pass 2 partials ----
        const bool prow = (r >= 2) && (r <= 13) && (gh_f < H);
        a0 = a1 = a2 = a3 = 0.f;
        if (isA) {
            if (prow) {
                const float* Q0 = st + (r - 2) * STS + 4 * s;
                ROW5(F0,F1,F2,F3,F4,   Q0)
                ROW5(F5,F6,F7,F8,F9,   Q0 + STS)
                ROW5(F10,F11,F12,F13,F14, Q0 + 2 * STS)
                *(f4*)&sp[r * STS + 4 * s] = f4{a0, a1, a2, a3};
            }
        } else {
            if (prow) {
                const float* Q3 = st + (r + 1) * STS + 4 * s;
                ROW5(F0,F1,F2,F3,F4,   Q3)
                ROW5(F5,F6,F7,F8,F9,   Q3 + STS)
            }
        }
        LBAR();   // b3: sp (pass-2 A-partials) visible

        if (!isA && prow) {            // combine -> global
            f4 q2 = *(const f4*)&sp[r * STS + 4 * s];
            float o0 = q2.x + a0, o1 = q2.y + a1, o2 = q2.z + a2, o3 = q2.w + a3;
            float* op = out + ((size_t)(n * C + c0 + cc) * H + gh_f) * W + gwb;
            if (s >= 1 && gwb + 1 < W)  *(f2*)op       = f2{o0, o1};
            if (s <= 14 && gwb + 3 < W) *(f2*)(op + 2) = f2{o2, o3};
        }

        // land prefetch into the other buffer
        if (pf && stg) *(f4*)&sx[cur ^ 1][l0] = nx;
        LBAR();   // b4: next-channel x visible
        cur ^= 1;
    }
}

extern "C" void kernel_launch(void* const* d_in, const int* in_sizes, int n_in,
                              void* d_out, int out_size, void* d_ws, size_t ws_size,
                              hipStream_t stream) {
    const float* x = (const float*)d_in[0];
    const float* f = (const float*)d_in[1];
    float* out = (float*)d_out;

    const int N = 2, C = 64, H = 256, W = 512;
    const int CPB = 32;                        // finer grain for load balance
    const int CG = C / CPB;                    // 2

    dim3 grid((W + OW - 1) / OW,               // 9
              (H + OH - 1) / OH,               // 22
              N * CG);                         // 4  -> 792 blocks of 512 thr
    lga2_fused<<<grid, 512, 0, stream>>>(x, f, out, N, C, H, W, CPB);
}